// Round 10
// baseline (247.754 us; speedup 1.0000x reference)
//
#include <hip/hip_runtime.h>
#include <math.h>

typedef _Float16 half4_t __attribute__((ext_vector_type(4)));
typedef _Float16 half8_t __attribute__((ext_vector_type(8)));
typedef __fp16   fp16x2  __attribute__((ext_vector_type(2)));
typedef float    f32x4   __attribute__((ext_vector_type(4)));

#define B_   32
#define NQ_  16384
#define NK_  31
#define DM_  64
#define BLK_PER_B 32      // 1024 blocks total
#define ITERS 8           // tiles per wave
#define RING  4           // LDS ring slots per wave (3 tiles in flight steady)
#define KSCALE 0.3606738222635048f   // 0.25 * log2(e)

#define AS1 __attribute__((address_space(1)))
#define AS3 __attribute__((address_space(3)))

static __device__ __forceinline__ half4_t cvt4(f32x4 f) {
  fp16x2 lo = __builtin_amdgcn_cvt_pkrtz(f[0], f[1]);
  fp16x2 hi = __builtin_amdgcn_cvt_pkrtz(f[2], f[3]);
  half4_t r;
  r[0] = (_Float16)lo[0]; r[1] = (_Float16)lo[1];
  r[2] = (_Float16)hi[0]; r[3] = (_Float16)hi[1];
  return r;
}

// ---------------------------------------------------------------------------
// Fused MHA + out-proj. Block = 4 waves, 80 KB LDS (16 KB VW^T + 64 KB Q ring).
// R9 retry: previous submission failed on container acquire (infra), not on
// the kernel -- vmcnt ledger and ring hazards re-audited (see session notes):
// issue order d3,s0,d4,s1,d5,s2 -> steady wait vmcnt(20) retires exactly
// d(t); dma(t+3) never touches the slot consumed/staged at t..t+2; staging
// ds_reads are lgkmcnt-gated before dma(t+4) reuses the slot. No hang mode.
// Experiment (unchanged): 3-deep DMA ring -> 96 KB/CU outstanding (2x R8),
// identical compute/patterns/stores. BW moves -> latency-bound confirmed;
// BW flat -> stream-rate cap = machine ceiling for this op.
// ---------------------------------------------------------------------------
__global__ __launch_bounds__(256) void attn(
    const float* __restrict__ Q, const float* __restrict__ K,
    const float* __restrict__ V, const unsigned char* __restrict__ mraw,
    const float* __restrict__ W, const float* __restrict__ bout,
    float* __restrict__ out) {
  int b    = blockIdx.x >> 5;             // 32 blocks per batch
  int blk  = blockIdx.x & 31;
  int tid  = threadIdx.x;
  int wave = tid >> 6, lane = tid & 63;
  int lq = lane & 15, quad = lane >> 4;

  // [s][pair][lane] : 16B per lane = {vw_dt(2p), vw_dt(2p+1)}
  __shared__ half8_t lds_vw[8][2][64];
  // per-wave 4-slot Q ring / store staging, XOR-swizzled layout
  __shared__ f32x4 lds_q[4][RING][16][16];

  const f32x4 fzero = {0.f, 0.f, 0.f, 0.f};
  int w = blk * 4 + wave;                 // 0..127 within batch
  const float* qbatch = Q + (size_t)b * NQ_ * DM_;

  // ---- async DMA of one 16x64 f32 Q tile into a ring slot ----
  auto dma_tile = [&](int it, int slot) {
    const float* qt = qbatch + (size_t)(w + it * 128) * 16 * DM_;
    #pragma unroll
    for (int j = 0; j < 4; ++j) {
      int row = 4 * j + quad;
      const float* src = qt + row * DM_ + ((lq ^ (row & 7)) << 2);
      __builtin_amdgcn_global_load_lds(
          (const AS1 void*)(const void*)src,
          (AS3 void*)(void*)((char*)&lds_q[wave][slot][0][0] + j * 1024),
          16, 0, 0);
    }
  };

  // tiles 0..2 in flight before any prologue work (drained by __syncthreads)
  dma_tile(0, 0);
  dma_tile(1, 1);
  dma_tile(2, 2);

  // ---- mask word (per-wave, ballot-based; dtype sniffed from raw bytes) ----
  unsigned mb;
  {
    unsigned char c0 = 0, c1 = 0;
    if (lane < 62) { c0 = mraw[2 * lane]; c1 = mraw[2 * lane + 1]; }
    unsigned long long m3f =
        __ballot(lane < 62 && (c0 == 0x3f || c1 == 0x3f));
    unsigned long long moff =
        __ballot(lane < 62 && ((((2 * lane) & 3) != 0 && c0 != 0) || c1 != 0));
    int mode = m3f ? 2 : (moff ? 0 : 1);
    int nz = 0;
    if (lane < NK_) {
      int idx = b * NK_ + lane;
      nz = (mode == 0) ? (mraw[idx] != 0)
         : (mode == 1) ? (((const int*)mraw)[idx] != 0)
                       : (((const float*)mraw)[idx] != 0.0f);
    }
    mb = (unsigned)__ballot(nz) & 0x7fffffffu;
  }

  // ---- mask bias for GEMM1's C operand (key 31 pad auto-masked) ----
  f32x4 cbias[2];
  #pragma unroll
  for (int tt = 0; tt < 2; ++tt)
    #pragma unroll
    for (int r = 0; r < 4; ++r) {
      int key = 16 * tt + 4 * quad + r;
      cbias[tt][r] = ((mb >> key) & 1u) ? 0.0f : -1e30f;
    }

  // ---- K fragments in registers (16 VGPR), scale folded ----
  half4_t kf[2][4];
  #pragma unroll
  for (int tt = 0; tt < 2; ++tt) {
    int k = 16 * tt + lq;
    #pragma unroll
    for (int h = 0; h < 4; ++h) {
      f32x4 f = fzero;
      if (k < NK_)
        f = *(const f32x4*)(K + ((size_t)b * NK_ + k) * DM_ + 16 * h + 4 * quad);
      kf[tt][h] = cvt4(f * KSCALE);
    }
  }

  // ---- VW^T fragments for dt = wave (8 prologue MFMAs) -> LDS ----
  {
    half4_t af[8];
    #pragma unroll
    for (int s = 0; s < 8; ++s) {
      int k = 16 * (s & 1) + lq, h = s >> 1;
      f32x4 f = fzero;
      if (k < NK_)
        f = *(const f32x4*)(V + ((size_t)b * NK_ + k) * DM_ + 16 * h + 4 * quad);
      af[s] = cvt4(f);
    }
    half4_t bf[4];
    #pragma unroll
    for (int h = 0; h < 4; ++h) {
      f32x4 f = *(const f32x4*)(W + (16 * wave + lq) * DM_ + 16 * h + 4 * quad);
      bf[h] = cvt4(f);
    }
    #pragma unroll
    for (int s = 0; s < 8; ++s) {
      f32x4 m = __builtin_amdgcn_mfma_f32_16x16x16f16(af[s], bf[s >> 1],
                                                      fzero, 0, 0, 0);
      ((half4_t*)&lds_vw[s][wave >> 1][lane])[wave & 1] = cvt4(m);
    }
  }

  // ---- bias fragments; GEMM2's C-operand init (const across queries) ----
  f32x4 bias[4];
  #pragma unroll
  for (int dt = 0; dt < 4; ++dt)
    bias[dt] = *(const f32x4*)(bout + 16 * dt + 4 * quad);

  __syncthreads();   // compiler emits vmcnt(0) drain: tiles 0..2 resident

  // ---- main loop: 3-deep DMA ring, counted vmcnt, no block barriers ----
  #pragma unroll
  for (int t = 0; t < ITERS; ++t) {
    const int slot = t & (RING - 1);

    // gate on THIS tile's DMA. Loop-issued vmem ops newer than d(t):
    // steady (3<=t<6): s(t-3)[4] d(t+1)[4] s(t-2)[4] d(t+2)[4] s(t-1)[4]=20
    // t==6: s3 d7 s4 s5 = 16 ; t==7: s4 s5 s6 = 12 ; t<3: pre-drained.
    if (t < 6)      asm volatile("s_waitcnt vmcnt(20)" ::: "memory");
    else if (t == 6) asm volatile("s_waitcnt vmcnt(16)" ::: "memory");
    else             asm volatile("s_waitcnt vmcnt(12)" ::: "memory");
    __builtin_amdgcn_sched_barrier(0);

    // Q fragment reads from swizzled LDS tile
    half4_t qf[4];
    #pragma unroll
    for (int h = 0; h < 4; ++h)
      qf[h] = cvt4(lds_q[wave][slot][lq][(4 * h + quad) ^ (lq & 7)]);

    // refill: issue tile t+3 into slot (t+3)&3 (that slot's staging reads
    // completed last iteration; DMA data lands well after)
    if (t + 3 < ITERS) dma_tile(t + 3, (t + 3) & (RING - 1));
    __builtin_amdgcn_sched_barrier(0);   // pin DMA before compute/stores

    // GEMM1 + per-head softmax (log2-domain scores -> exp2)
    half4_t pf[8];
    #pragma unroll
    for (int h = 0; h < 4; ++h) {
      f32x4 c0 = __builtin_amdgcn_mfma_f32_16x16x16f16(kf[0][h], qf[h], cbias[0], 0, 0, 0);
      f32x4 c1 = __builtin_amdgcn_mfma_f32_16x16x16f16(kf[1][h], qf[h], cbias[1], 0, 0, 0);
      f32x4 e0, e1;
      #pragma unroll
      for (int r = 0; r < 4; ++r) {
        e0[r] = __builtin_amdgcn_exp2f(c0[r]);
        e1[r] = __builtin_amdgcn_exp2f(c1[r]);
      }
      float sum = (e0[0] + e0[1]) + (e0[2] + e0[3]) +
                  (e1[0] + e1[1]) + (e1[2] + e1[3]);
      sum += __shfl_xor(sum, 16);
      sum += __shfl_xor(sum, 32);
      float inv = (sum > 0.f) ? __builtin_amdgcn_rcpf(sum) : 0.f;
      pf[2 * h + 0] = cvt4(e0 * inv);
      pf[2 * h + 1] = cvt4(e1 * inv);
    }

    // GEMM2; C operand starts at bias
    f32x4 acc[4] = {bias[0], bias[1], bias[2], bias[3]};
    #pragma unroll
    for (int s = 0; s < 8; ++s) {
      half8_t v01 = lds_vw[s][0][lane];
      half8_t v23 = lds_vw[s][1][lane];
      half4_t a0 = __builtin_shufflevector(v01, v01, 0, 1, 2, 3);
      half4_t a1 = __builtin_shufflevector(v01, v01, 4, 5, 6, 7);
      half4_t a2 = __builtin_shufflevector(v23, v23, 0, 1, 2, 3);
      half4_t a3 = __builtin_shufflevector(v23, v23, 4, 5, 6, 7);
      acc[0] = __builtin_amdgcn_mfma_f32_16x16x16f16(a0, pf[s], acc[0], 0, 0, 0);
      acc[1] = __builtin_amdgcn_mfma_f32_16x16x16f16(a1, pf[s], acc[1], 0, 0, 0);
      acc[2] = __builtin_amdgcn_mfma_f32_16x16x16f16(a2, pf[s], acc[2], 0, 0, 0);
      acc[3] = __builtin_amdgcn_mfma_f32_16x16x16f16(a3, pf[s], acc[3], 0, 0, 0);
    }

    // store staging through the freed slot (same swizzle), then 4x1KB stores
    #pragma unroll
    for (int dt = 0; dt < 4; ++dt)
      lds_q[wave][slot][lq][(4 * dt + quad) ^ (lq & 7)] = acc[dt];

    float* ot = out + ((size_t)b * NQ_ + (size_t)(w + t * 128) * 16) * DM_;
    #pragma unroll
    for (int j = 0; j < 4; ++j) {
      int row = 4 * j + quad;
      f32x4 ov = lds_q[wave][slot][row][lq ^ (row & 7)];
      *(f32x4*)(ot + row * DM_ + lq * 4) = ov;
    }
  }
}

extern "C" void kernel_launch(void* const* d_in, const int* in_sizes, int n_in,
                              void* d_out, int out_size, void* d_ws, size_t ws_size,
                              hipStream_t stream) {
  const float*         Q    = (const float*)d_in[0];
  const float*         K    = (const float*)d_in[1];
  const float*         V    = (const float*)d_in[2];
  const unsigned char* mask = (const unsigned char*)d_in[3];
  const float*         W    = (const float*)d_in[4];
  const float*         bo   = (const float*)d_in[5];
  float*               out  = (float*)d_out;

  hipLaunchKernelGGL(attn, dim3(B_ * BLK_PER_B), dim3(256), 0, stream,
                     Q, K, V, mask, W, bo, out);
}